// Round 10
// baseline (144.703 us; speedup 1.0000x reference)
//
#include <hip/hip_runtime.h>
#include <math.h>

#define SN  512
#define NN  128
#define CIN 32
#define CA  5
#define HH  64
#define YY  96
#define H3  128
#define H4  64
#define EPSF 1e-7f

typedef __attribute__((ext_vector_type(8))) short  bf16x8;
typedef __attribute__((ext_vector_type(4))) float  f32x4;
typedef __attribute__((ext_vector_type(4))) unsigned short us4;

#define MFMA16 __builtin_amdgcn_mfma_f32_16x16x32_bf16

__device__ inline unsigned short f2b(float f) {
    unsigned u = __builtin_bit_cast(unsigned, f);
    return (unsigned short)((u + 0x7FFFu + ((u >> 16) & 1u)) >> 16);
}
__device__ inline float b2f(unsigned short h) {
    unsigned u = ((unsigned)h) << 16;
    return __builtin_bit_cast(float, u);
}
__device__ inline bf16x8 pack8(float4 f0, float4 f1) {
    bf16x8 v;
    v[0]=(short)f2b(f0.x); v[1]=(short)f2b(f0.y); v[2]=(short)f2b(f0.z); v[3]=(short)f2b(f0.w);
    v[4]=(short)f2b(f1.x); v[5]=(short)f2b(f1.y); v[6]=(short)f2b(f1.z); v[7]=(short)f2b(f1.w);
    return v;
}
// PART (bf16): [p][ir16][b64], col rotated by ir>>2 for bank spread.
__device__ inline int part_idx(int p, int ir, int col) {
    return p*1024 + ir*64 + ((col + (ir>>2)*16) & 63);
}

// ws pack (bf16): W1p [c5][b64][a32] @0 | W2p [c5][b64][a96] @10240 | nwp [b128][a96] @40960
__global__ __launch_bounds__(512) void pack_weights(
    const float* __restrict__ w1, const float* __restrict__ lw1,
    const float* __restrict__ w2, const float* __restrict__ lw2,
    const float* __restrict__ nw, unsigned short* __restrict__ wp)
{
    int t = blockIdx.x*512 + threadIdx.x;
    if (t < 10240) {
        int c = t >> 11, rem = t & 2047, b = rem >> 5, a = rem & 31;
        float v = (c < 4) ? w1[(a*64+b)*4 + c] : lw1[a*64+b];
        wp[t] = f2b(v);
    } else if (t < 40960) {
        int u = t - 10240;
        int c = u / 6144, rem = u % 6144, b = rem / 96, a = rem % 96;
        float v = (c < 4) ? w2[(a*64+b)*4 + c] : lw2[a*64+b];
        wp[t] = f2b(v);
    } else {
        int u = t - 40960;
        int b = u / 96, a = u % 96;
        wp[t] = f2b(nw[a*128 + b]);
    }
}

template<bool FIRST>
__device__ __forceinline__ void load_yfrags(
    const float* __restrict__ xg, const unsigned short* __restrict__ h1s,
    int row, int kg, bf16x8* yf)
{
    if constexpr (FIRST) {
        float4 f0 = *(const float4*)(xg + row*CIN + kg*8);
        float4 f1 = *(const float4*)(xg + row*CIN + kg*8 + 4);
        yf[0] = pack8(f0, f1);
    } else {
        yf[0] = *(const bf16x8*)&h1s[row*HH + kg*8];
        yf[1] = *(const bf16x8*)&h1s[row*HH + 32 + kg*8];
        float4 f0 = *(const float4*)(xg + row*CIN + kg*8);
        float4 f1 = *(const float4*)(xg + row*CIN + kg*8 + 4);
        yf[2] = pack8(f0, f1);
    }
}

// conv kernel: one block per (sample, half g). 8 waves; wave-pair (p,h):
// p = i-tile (g*64+p*16), h = channel half {2h,2h+1}.
// Per jt (32 j): all-wave P-slice GEMM -> PZ [c][64b][40j-pad]; pair-shared
// A de-interleave -> scr; MFMA accumulate (+ones rowsums for FIRST).
template<int CINY, bool FIRST>
__global__ __launch_bounds__(512) void conv_kernel(
    const float* __restrict__ A, const float* __restrict__ x,
    const unsigned short* __restrict__ h1g,
    const unsigned short* __restrict__ wp,
    const float* __restrict__ LB,
    float* __restrict__ invg,
    unsigned short* __restrict__ outg)
{
    constexpr int K32  = CINY / 32;
    constexpr int WOFF = FIRST ? 0 : 10240;
    __shared__ __align__(16) char smem[50176];
    short* SCR = (short*)smem;                       // 4 x [16][168] = 21504 B
    short* PZ  = (short*)(smem + 21504);             // [4][64][40]   = 20480 B
    unsigned short* PART = (unsigned short*)(smem + 41984); // [4][16][64] = 8192 B

    const int bx = blockIdx.x, s = bx >> 1, g = bx & 1;
    const int tid = threadIdx.x;
    const int wave = tid>>6, lane = tid&63, lm = lane&15, kg = lane>>4;
    const int p = wave >> 1, h = wave & 1;
    const float* xg = x + (size_t)s*NN*CIN;
    const unsigned short* h1s = h1g + (size_t)s*NN*HH;

    // ---- linear channel (c=4) for this block's i-rows -> PART ----
    {
        bf16x8 yf[K32];
        load_yfrags<FIRST>(xg, h1s, g*64 + p*16 + lm, kg, yf);
        #pragma unroll
        for (int n2 = 0; n2 < 2; ++n2) {
            const int n = h*2 + n2;
            f32x4 pc = (f32x4){0.f,0.f,0.f,0.f};
            #pragma unroll
            for (int ks = 0; ks < K32; ++ks) {
                const bf16x8 bw = *(const bf16x8*)&wp[WOFF + (4*64 + n*16+lm)*CINY + ks*32 + kg*8];
                pc = MFMA16(yf[ks], bw, pc, 0,0,0);
            }
            #pragma unroll
            for (int r = 0; r < 4; ++r)
                PART[part_idx(p, kg*4+r, n*16+lm)] = f2b(pc[r]);
        }
    }

    float iv[2][4];
    if constexpr (!FIRST) {   // issue inv loads early (produced by conv1)
        const int ib = (s*NN + g*64 + p*16 + kg*4)*4;
        #pragma unroll
        for (int cl = 0; cl < 2; ++cl)
            #pragma unroll
            for (int r = 0; r < 4; ++r)
                iv[cl][r] = invg[ib + r*4 + 2*h + cl];
    }
    __syncthreads();

    // ---- jt loop ----
    f32x4 acc[2][4];
    #pragma unroll
    for (int cl=0;cl<2;++cl)
        #pragma unroll
        for (int n=0;n<4;++n) acc[cl][n] = (f32x4){0.f,0.f,0.f,0.f};
    f32x4 sums[2];
    if constexpr (FIRST) {
        sums[0] = (f32x4){0.f,0.f,0.f,0.f};
        sums[1] = (f32x4){0.f,0.f,0.f,0.f};
    }
    bf16x8 ones;
    #pragma unroll
    for (int q = 0; q < 8; ++q) ones[q] = (short)0x3F80;

    const int r8 = lane>>3, l8 = lane&7;
    const int rr = r8 + 8*h;
    const float* Ab = A + ((size_t)(s*NN + g*64 + p*16 + rr))*NN*CA;
    short* scr = SCR + p*2688;
    const int cP = wave >> 1, jj = wave & 1;   // P-GEMM duty

    for (int jt = 0; jt < 4; ++jt) {
        // A prefetch (consumed after next barrier; latency hides under P-GEMM)
        const float* rp = Ab + jt*160 + l8*20;
        const float4 q0 = *(const float4*)(rp);
        const float4 q1 = *(const float4*)(rp+4);
        const float4 q2 = *(const float4*)(rp+8);
        const float4 q3 = *(const float4*)(rp+12);
        const float4 q4 = *(const float4*)(rp+16);

        // P-slice GEMM: wave (cP, jj) -> P[cP][*][jj*16..+16]
        {
            bf16x8 yf[K32];
            load_yfrags<FIRST>(xg, h1s, jt*32 + jj*16 + lm, kg, yf);
            #pragma unroll
            for (int n = 0; n < 4; ++n) {
                f32x4 pc = (f32x4){0.f,0.f,0.f,0.f};
                #pragma unroll
                for (int ks = 0; ks < K32; ++ks) {
                    const bf16x8 bw = *(const bf16x8*)&wp[WOFF + (cP*64 + n*16+lm)*CINY + ks*32 + kg*8];
                    pc = MFMA16(yf[ks], bw, pc, 0,0,0);
                }
                us4 w;
                w[0]=f2b(pc[0]); w[1]=f2b(pc[1]); w[2]=f2b(pc[2]); w[3]=f2b(pc[3]);
                *(us4*)&PZ[(cP*64 + n*16+lm)*40 + jj*16 + kg*4] = w;
            }
        }
        __syncthreads();

        // stage A -> scr (pair-shared de-interleave)
        {
            short* lr = scr + rr*168;
            const int jb = 4*l8;
            lr[0*40 + jb+0] = (short)f2b(q0.x);
            lr[1*40 + jb+0] = (short)f2b(q0.y);
            lr[2*40 + jb+0] = (short)f2b(q0.z);
            lr[3*40 + jb+0] = (short)f2b(q0.w);
            lr[0*40 + jb+1] = (short)f2b(q1.y);
            lr[1*40 + jb+1] = (short)f2b(q1.z);
            lr[2*40 + jb+1] = (short)f2b(q1.w);
            lr[3*40 + jb+1] = (short)f2b(q2.x);
            lr[0*40 + jb+2] = (short)f2b(q2.z);
            lr[1*40 + jb+2] = (short)f2b(q2.w);
            lr[2*40 + jb+2] = (short)f2b(q3.x);
            lr[3*40 + jb+2] = (short)f2b(q3.y);
            lr[0*40 + jb+3] = (short)f2b(q3.w);
            lr[1*40 + jb+3] = (short)f2b(q4.x);
            lr[2*40 + jb+3] = (short)f2b(q4.y);
            lr[3*40 + jb+3] = (short)f2b(q4.z);
        }
        __syncthreads();

        // main MFMA
        {
            const bf16x8 A0 = *(const bf16x8*)&scr[lm*168 + (2*h  )*40 + kg*8];
            const bf16x8 A1 = *(const bf16x8*)&scr[lm*168 + (2*h+1)*40 + kg*8];
            #pragma unroll
            for (int n = 0; n < 4; ++n) {
                const bf16x8 b0 = *(const bf16x8*)&PZ[((2*h  )*64 + n*16+lm)*40 + kg*8];
                acc[0][n] = MFMA16(A0, b0, acc[0][n], 0,0,0);
                const bf16x8 b1 = *(const bf16x8*)&PZ[((2*h+1)*64 + n*16+lm)*40 + kg*8];
                acc[1][n] = MFMA16(A1, b1, acc[1][n], 0,0,0);
            }
            if constexpr (FIRST) {
                sums[0] = MFMA16(A0, ones, sums[0], 0,0,0);
                sums[1] = MFMA16(A1, ones, sums[1], 0,0,0);
            }
        }
        __syncthreads();
    }

    // ---- epilogue ----
    if constexpr (FIRST) {
        #pragma unroll
        for (int cl = 0; cl < 2; ++cl)
            #pragma unroll
            for (int r = 0; r < 4; ++r)
                iv[cl][r] = 1.0f/(sums[cl][r] + EPSF);
        if (lm == 0) {
            const int ib = (s*NN + g*64 + p*16 + kg*4)*4;
            #pragma unroll
            for (int cl = 0; cl < 2; ++cl)
                #pragma unroll
                for (int r = 0; r < 4; ++r)
                    invg[ib + r*4 + 2*h + cl] = iv[cl][r];
        }
    }
    if (h) {   // fold channels {2,3} into PART (holds linear term)
        #pragma unroll
        for (int n = 0; n < 4; ++n)
            #pragma unroll
            for (int r = 0; r < 4; ++r) {
                const int idx = part_idx(p, kg*4+r, n*16+lm);
                PART[idx] = f2b(b2f(PART[idx])
                              + acc[0][n][r]*iv[0][r] + acc[1][n][r]*iv[1][r]);
            }
    }
    __syncthreads();
    if (!h) {  // combine + bias + tanh -> global bf16 [s*128+i][64]
        #pragma unroll
        for (int n = 0; n < 4; ++n) {
            const float lbv = LB[n*16 + lm];
            #pragma unroll
            for (int r = 0; r < 4; ++r) {
                float vv = lbv
                    + acc[0][n][r]*iv[0][r] + acc[1][n][r]*iv[1][r]
                    + b2f(PART[part_idx(p, kg*4+r, n*16+lm)]);
                outg[(size_t)(s*NN + g*64 + p*16 + kg*4 + r)*HH + n*16 + lm] = f2b(tanhf(vv));
            }
        }
    }
}

// pool + head: one block (512 thr) per sample.
__global__ __launch_bounds__(512) void pool_kernel(
    const unsigned short* __restrict__ h2g, const float* __restrict__ x,
    const unsigned short* __restrict__ wp,
    const float* __restrict__ gw, const float* __restrict__ gb,
    const float* __restrict__ nb,
    const float* __restrict__ l3w, const float* __restrict__ l3b,
    const float* __restrict__ l4w, const float* __restrict__ l4b,
    const float* __restrict__ l5w, const float* __restrict__ l5b,
    float* __restrict__ out)
{
    __shared__ __align__(16) char smem[32256];
    short* xcb  = (short*)smem;               // [128][104] bf16
    float* part = (float*)(smem + 26624);     // [8][128]
    float* gate = (float*)(smem + 30720);
    float* red  = (float*)(smem + 31232);
    float* tmpv = (float*)(smem + 31744);

    const int s = blockIdx.x, tid = threadIdx.x;
    const int wave = tid>>6, lane = tid&63, lm = lane&15, kg = lane>>4;
    const float* xg = x + (size_t)s*NN*CIN;
    const unsigned short* h2s = h2g + (size_t)s*NN*HH;

    for (int t = tid; t < NN*16; t += 512) {
        const int row = t >> 4, c4 = t & 15;
        *(us4*)&xcb[row*104 + c4*4] = *(const us4*)&h2s[row*HH + c4*4];
    }
    for (int t = tid; t < NN*CIN; t += 512)
        xcb[(t>>5)*104 + 64 + (t&31)] = (short)f2b(xg[t]);
    __syncthreads();

    // gate logits: 4 threads per node
    {
        const int i = tid >> 2, t4 = tid & 3;
        float z = 0.f;
        #pragma unroll
        for (int q = 0; q < 24; ++q) {
            const int a = t4*24 + q;
            z += b2f((unsigned short)xcb[i*104 + a]) * gw[a];
        }
        z += __shfl_xor(z, 1); z += __shfl_xor(z, 2);
        if (t4 == 0) red[i] = z + gb[0];
    }
    __syncthreads();
    if (wave == 0) {   // softmax over 128 nodes
        float v0 = red[lane], v1 = red[lane + 64];
        float m = fmaxf(v0, v1);
        #pragma unroll
        for (int off = 32; off > 0; off >>= 1) m = fmaxf(m, __shfl_xor(m, off));
        float e0 = expf(v0 - m), e1 = expf(v1 - m);
        float ssum = e0 + e1;
        #pragma unroll
        for (int off = 32; off > 0; off >>= 1) ssum += __shfl_xor(ssum, off);
        gate[lane] = e0 / ssum; gate[lane + 64] = e1 / ssum;
    }
    __syncthreads();

    // pooled GEMM: wave = i-tile (8 x 16 rows), all 8 column tiles
    {
        f32x4 pacc[8];
        #pragma unroll
        for (int nt=0;nt<8;++nt) pacc[nt] = (f32x4){0.f,0.f,0.f,0.f};
        #pragma unroll
        for (int ks=0;ks<3;++ks) {
            const bf16x8 afp = *(const bf16x8*)&xcb[(wave*16+lm)*104 + ks*32 + kg*8];
            #pragma unroll
            for (int nt=0;nt<8;++nt) {
                const bf16x8 bfp = *(const bf16x8*)&wp[40960 + (nt*16+lm)*96 + ks*32 + kg*8];
                pacc[nt] = MFMA16(afp, bfp, pacc[nt], 0,0,0);
            }
        }
        #pragma unroll
        for (int nt=0;nt<8;++nt) {
            const float nbv = nb[nt*16+lm];
            float pv = 0.f;
            #pragma unroll
            for (int r=0;r<4;++r)
                pv += gate[wave*16 + kg*4 + r] * tanhf(pacc[nt][r] + nbv);
            pv += __shfl_xor(pv, 16);
            pv += __shfl_xor(pv, 32);
            if (lane < 16) part[wave*128 + nt*16 + lm] = pv;
        }
    }
    __syncthreads();
    if (tid < H3) {
        float pooled = 0.f;
        #pragma unroll
        for (int w = 0; w < 8; ++w) pooled += part[w*128 + tid];
        tmpv[tid] = tanhf(pooled);                 // h3
    }
    __syncthreads();
    if (tid < H3) {
        float a4 = l3b[tid];
        for (int aa = 0; aa < H3; ++aa) a4 += tmpv[aa] * l3w[aa*H3 + tid];
        red[tid] = tanhf(a4);                      // h4
    }
    __syncthreads();
    if (tid < H4) {
        float a5 = l4b[tid];
        for (int aa = 0; aa < H3; ++aa) a5 += red[aa] * l4w[aa*H4 + tid];
        gate[tid] = tanhf(a5);                     // h5
    }
    __syncthreads();
    if (tid == 0) {
        float zo = l5b[0];
        for (int aa = 0; aa < H4; ++aa) zo += gate[aa] * l5w[aa];
        out[s] = 1.0f / (1.0f + expf(-zo));
    }
}

extern "C" void kernel_launch(void* const* d_in, const int* in_sizes, int n_in,
                              void* d_out, int out_size, void* d_ws, size_t ws_size,
                              hipStream_t stream)
{
    const float* A   = (const float*)d_in[0];
    const float* x   = (const float*)d_in[1];
    const float* w1  = (const float*)d_in[2];
    const float* lw1 = (const float*)d_in[3];
    const float* lb1 = (const float*)d_in[4];
    const float* w2  = (const float*)d_in[5];
    const float* lw2 = (const float*)d_in[6];
    const float* lb2 = (const float*)d_in[7];
    const float* gw  = (const float*)d_in[8];
    const float* gb  = (const float*)d_in[9];
    const float* nw  = (const float*)d_in[10];
    const float* nb  = (const float*)d_in[11];
    const float* l3w = (const float*)d_in[12];
    const float* l3b = (const float*)d_in[13];
    const float* l4w = (const float*)d_in[14];
    const float* l4b = (const float*)d_in[15];
    const float* l5w = (const float*)d_in[16];
    const float* l5b = (const float*)d_in[17];
    float* out = (float*)d_out;

    unsigned short* wp   = (unsigned short*)d_ws;                       // 106,496 B
    unsigned short* h1g  = (unsigned short*)((char*)d_ws + 131072);     // 8,388,608 B
    unsigned short* h2g  = (unsigned short*)((char*)d_ws + 8519680);    // 8,388,608 B
    float*          invg = (float*)((char*)d_ws + 16908288);            // 1,048,576 B

    pack_weights<<<104, 512, 0, stream>>>(w1, lw1, w2, lw2, nw, wp);
    conv_kernel<CIN, true ><<<SN*2, 512, 0, stream>>>(A, x, h1g, wp, lb1, invg, h1g);
    conv_kernel<YY,  false><<<SN*2, 512, 0, stream>>>(A, x, h1g, wp, lb2, invg, h2g);
    pool_kernel<<<SN, 512, 0, stream>>>(h2g, x, wp, gw, gb, nb,
                                        l3w, l3b, l4w, l4b, l5w, l5b, out);
}

// Round 11
// 106.919 us; speedup vs baseline: 1.3534x; 1.3534x over previous
//
#include <hip/hip_runtime.h>
#include <math.h>

#define SN  512
#define NN  128
#define CIN 32
#define CA  5
#define HH  64
#define YY  96
#define H3  128
#define H4  64
#define EPSF 1e-7f

typedef __attribute__((ext_vector_type(8))) short  bf16x8;
typedef __attribute__((ext_vector_type(4))) float  f32x4;
typedef __attribute__((ext_vector_type(4))) unsigned short us4;

#define MFMA16 __builtin_amdgcn_mfma_f32_16x16x32_bf16

__device__ inline unsigned short f2b(float f) {
    unsigned u = __builtin_bit_cast(unsigned, f);
    return (unsigned short)((u + 0x7FFFu + ((u >> 16) & 1u)) >> 16);
}
__device__ inline float b2f(unsigned short h) {
    unsigned u = ((unsigned)h) << 16;
    return __builtin_bit_cast(float, u);
}
__device__ inline bf16x8 pack8(float4 f0, float4 f1) {
    bf16x8 v;
    v[0]=(short)f2b(f0.x); v[1]=(short)f2b(f0.y); v[2]=(short)f2b(f0.z); v[3]=(short)f2b(f0.w);
    v[4]=(short)f2b(f1.x); v[5]=(short)f2b(f1.y); v[6]=(short)f2b(f1.z); v[7]=(short)f2b(f1.w);
    return v;
}
__device__ inline bf16x8 scale8(bf16x8 a, float s) {
    bf16x8 o;
    #pragma unroll
    for (int q = 0; q < 8; ++q)
        o[q] = (short)f2b(b2f((unsigned short)a[q]) * s);
    return o;
}

// PZ: 320 rows (c0..c4 x 64 b) x 128 shorts, XOR-swizzled 16B chunks. 80 KiB.
__device__ inline void pz_store4(short* PZ, int row, int colsh, const f32x4& pc) {
    int byo = (colsh*2) ^ ((row & 7) << 4);
    us4 w;
    w[0]=f2b(pc[0]); w[1]=f2b(pc[1]); w[2]=f2b(pc[2]); w[3]=f2b(pc[3]);
    *(us4*)&PZ[row*128 + (byo >> 1)] = w;
}
__device__ inline bf16x8 pz_load8(const short* PZ, int row, int colsh) {
    int byo = (colsh*2) ^ ((row & 7) << 4);
    return *(const bf16x8*)&PZ[row*128 + (byo >> 1)];
}
__device__ inline float pz_load1(const short* PZ, int row, int colsh) {
    int byo = (colsh*2) ^ ((row & 7) << 4);
    return b2f((unsigned short)PZ[row*128 + (byo >> 1)]);
}

// ws pack (bf16): W1p [c5][b64][a32] @0 | W2p [c5][b64][a96] @10240 | nwp [b128][a96] @40960
__global__ __launch_bounds__(512) void pack_weights(
    const float* __restrict__ w1, const float* __restrict__ lw1,
    const float* __restrict__ w2, const float* __restrict__ lw2,
    const float* __restrict__ nw, unsigned short* __restrict__ wp)
{
    int t = blockIdx.x*512 + threadIdx.x;
    if (t < 10240) {
        int c = t >> 11, rem = t & 2047, b = rem >> 5, a = rem & 31;
        float v = (c < 4) ? w1[(a*64+b)*4 + c] : lw1[a*64+b];
        wp[t] = f2b(v);
    } else if (t < 40960) {
        int u = t - 10240;
        int c = u / 6144, rem = u % 6144, b = rem / 96, a = rem % 96;
        float v = (c < 4) ? w2[(a*64+b)*4 + c] : lw2[a*64+b];
        wp[t] = f2b(v);
    } else {
        int u = t - 40960;
        int b = u / 96, a = u % 96;
        wp[t] = f2b(nw[a*128 + b]);
    }
}

// One conv stage. Wave owns i/j-tile = wave*16 and ALL channels.
// P-phase: P_c[j,b] (c=0..4, c4 = linear/LW channel) -> PZ swizzled.
// Main: acc[n] accumulates over jt AND c (A-frags are prenormalized).
template<int CINY>
__device__ __forceinline__ void conv_core(
    const unsigned short* __restrict__ wp, const float* __restrict__ LB,
    short* PZ, const bf16x8 (&Af)[4][4], const bf16x8* yf,
    float (&v)[4][4], int wave, int lm, int kg)
{
    constexpr int K32  = CINY / 32;
    constexpr int WOFF = (CINY == 32) ? 0 : 10240;

    #pragma unroll
    for (int c = 0; c < 5; ++c) {
        f32x4 pc[4];
        #pragma unroll
        for (int n = 0; n < 4; ++n) pc[n] = (f32x4){0.f,0.f,0.f,0.f};
        #pragma unroll
        for (int ks = 0; ks < K32; ++ks) {
            #pragma unroll
            for (int n = 0; n < 4; ++n) {
                const bf16x8 bw = *(const bf16x8*)&wp[WOFF + (c*64 + n*16+lm)*CINY + ks*32 + kg*8];
                pc[n] = MFMA16(yf[ks], bw, pc[n], 0,0,0);
            }
        }
        #pragma unroll
        for (int n = 0; n < 4; ++n)
            pz_store4(PZ, c*64 + n*16+lm, wave*16 + kg*4, pc[n]);
    }
    __syncthreads();

    f32x4 acc[4];
    #pragma unroll
    for (int n = 0; n < 4; ++n) acc[n] = (f32x4){0.f,0.f,0.f,0.f};
    #pragma unroll
    for (int jt = 0; jt < 4; ++jt) {
        #pragma unroll
        for (int c = 0; c < 4; ++c) {
            #pragma unroll
            for (int n = 0; n < 4; ++n) {
                const bf16x8 bp = pz_load8(PZ, c*64 + n*16+lm, jt*32 + kg*8);
                acc[n] = MFMA16(Af[jt][c], bp, acc[n], 0,0,0);
            }
        }
    }

    #pragma unroll
    for (int n = 0; n < 4; ++n) {
        const float lbv = LB[n*16 + lm];
        #pragma unroll
        for (int r = 0; r < 4; ++r) {
            const int i = wave*16 + kg*4 + r;
            v[n][r] = tanhf(lbv + acc[n][r] + pz_load1(PZ, 256 + n*16+lm, i));
        }
    }
    __syncthreads();   // all PZ reads done -> region reusable
}

__global__ __launch_bounds__(512, 2) void fused_kernel(
    const float* __restrict__ A, const float* __restrict__ x,
    const unsigned short* __restrict__ wp,
    const float* __restrict__ lb1, const float* __restrict__ lb2,
    const float* __restrict__ gw, const float* __restrict__ gb,
    const float* __restrict__ nb,
    const float* __restrict__ l3w, const float* __restrict__ l3b,
    const float* __restrict__ l4w, const float* __restrict__ l4b,
    const float* __restrict__ l5w, const float* __restrict__ l5b,
    float* __restrict__ out)
{
    __shared__ __align__(16) char smem[81920];
    short* PZ = (short*)smem;                 // 320 x 128 sh (full 80 KiB)
    // pool aliases (PZ dead by then)
    short* xcb  = (short*)smem;               // [128][104] bf16
    float* part = (float*)(smem + 26624);     // [8][128]
    float* gate = (float*)(smem + 30720);
    float* red  = (float*)(smem + 31232);
    float* tmpv = (float*)(smem + 31744);

    const int s = blockIdx.x, tid = threadIdx.x;
    const int wave = tid>>6, lane = tid&63, lm = lane&15, kg = lane>>4;
    const float* xg = x + (size_t)s*NN*CIN;

    const int jrow = wave*16 + lm;
    bf16x8 xfrag;
    {
        float4 f0 = *(const float4*)(xg + jrow*CIN + kg*8);
        float4 f1 = *(const float4*)(xg + jrow*CIN + kg*8 + 4);
        xfrag = pack8(f0, f1);
    }

    // ===== A prepass (wave-private, barrier-free): coalesced loads ->
    // de-interleave via scr -> raw Af; row-sums via q-components + shuffles;
    // prenormalize Af by 1/(rowsum+eps). =====
    bf16x8 Af[4][4];
    {
        short* scr = PZ + wave*2688;          // wave-private [16][168]
        const float* Ab = A + ((size_t)(s*NN + wave*16))*NN*CA;
        const int r8 = lane>>3, l8 = lane&7;
        float sm[2][4];
        #pragma unroll
        for (int rh = 0; rh < 2; ++rh)
            #pragma unroll
            for (int c = 0; c < 4; ++c) sm[rh][c] = 0.f;

        #pragma unroll
        for (int jt = 0; jt < 4; ++jt) {
            #pragma unroll
            for (int rh = 0; rh < 2; ++rh) {
                const int r = r8 + rh*8;
                const float* rp = Ab + (size_t)r*(NN*CA) + jt*160 + l8*20;
                float4 q0 = *(const float4*)(rp);
                float4 q1 = *(const float4*)(rp+4);
                float4 q2 = *(const float4*)(rp+8);
                float4 q3 = *(const float4*)(rp+12);
                float4 q4 = *(const float4*)(rp+16);
                short* lr = scr + r*168;
                const int jb = 4*l8;
                lr[0*40 + jb+0] = (short)f2b(q0.x);
                lr[1*40 + jb+0] = (short)f2b(q0.y);
                lr[2*40 + jb+0] = (short)f2b(q0.z);
                lr[3*40 + jb+0] = (short)f2b(q0.w);
                lr[0*40 + jb+1] = (short)f2b(q1.y);
                lr[1*40 + jb+1] = (short)f2b(q1.z);
                lr[2*40 + jb+1] = (short)f2b(q1.w);
                lr[3*40 + jb+1] = (short)f2b(q2.x);
                lr[0*40 + jb+2] = (short)f2b(q2.z);
                lr[1*40 + jb+2] = (short)f2b(q2.w);
                lr[2*40 + jb+2] = (short)f2b(q3.x);
                lr[3*40 + jb+2] = (short)f2b(q3.y);
                lr[0*40 + jb+3] = (short)f2b(q3.w);
                lr[1*40 + jb+3] = (short)f2b(q4.x);
                lr[2*40 + jb+3] = (short)f2b(q4.y);
                lr[3*40 + jb+3] = (short)f2b(q4.z);
                sm[rh][0] += q0.x + q1.y + q2.z + q3.w;
                sm[rh][1] += q0.y + q1.z + q2.w + q4.x;
                sm[rh][2] += q0.z + q1.w + q3.x + q4.y;
                sm[rh][3] += q0.w + q2.x + q3.y + q4.z;
            }
            #pragma unroll
            for (int c = 0; c < 4; ++c)
                Af[jt][c] = *(const bf16x8*)&scr[lm*168 + c*40 + kg*8];
        }
        // reduce row-sums across the 8 lanes (l8) covering each row
        #pragma unroll
        for (int off = 1; off < 8; off <<= 1) {
            #pragma unroll
            for (int rh = 0; rh < 2; ++rh)
                #pragma unroll
                for (int c = 0; c < 4; ++c)
                    sm[rh][c] += __shfl_xor(sm[rh][c], off);
        }
        float* invL = (float*)scr;            // scr dead after Af extraction
        if (l8 == 0) {
            #pragma unroll
            for (int rh = 0; rh < 2; ++rh)
                #pragma unroll
                for (int c = 0; c < 4; ++c)
                    invL[(r8 + rh*8)*4 + c] = 1.0f/(sm[rh][c] + EPSF);
        }
        const f32x4 iv = *(const f32x4*)&invL[lm*4];
        #pragma unroll
        for (int jt = 0; jt < 4; ++jt)
            #pragma unroll
            for (int c = 0; c < 4; ++c)
                Af[jt][c] = scale8(Af[jt][c], iv[c]);
    }
    __syncthreads();   // scr region (PZ) fully consumed

    // ===== conv1 =====
    float v[4][4];
    {
        bf16x8 yf1[1] = {xfrag};
        conv_core<CIN>(wp, lb1, PZ, Af, yf1, v, wave, lm, kg);
    }

    // h1 bounce (wave-private): (i,b) regs -> (j,a) fragments
    bf16x8 yf2[3];
    {
        short* scr = PZ + wave*2688;
        #pragma unroll
        for (int n = 0; n < 4; ++n)
            #pragma unroll
            for (int r = 0; r < 4; ++r)
                scr[(kg*4+r)*72 + n*16 + lm] = (short)f2b(v[n][r]);
        yf2[0] = *(const bf16x8*)&scr[lm*72 + kg*8];
        yf2[1] = *(const bf16x8*)&scr[lm*72 + 32 + kg*8];
        yf2[2] = xfrag;
    }
    __syncthreads();   // scr reads done before conv2 P-writes to PZ

    // ===== conv2 =====
    conv_core<YY>(wp, lb2, PZ, Af, yf2, v, wave, lm, kg);

    // ===== pool + head =====
    #pragma unroll
    for (int n = 0; n < 4; ++n)
        #pragma unroll
        for (int r = 0; r < 4; ++r)
            xcb[(wave*16 + kg*4 + r)*104 + n*16 + lm] = (short)f2b(v[n][r]);
    for (int t = tid; t < NN*CIN; t += 512)
        xcb[(t>>5)*104 + 64 + (t&31)] = (short)f2b(xg[t]);
    __syncthreads();

    // gate logits: 4 threads per node
    {
        const int i = tid >> 2, t4 = tid & 3;
        float z = 0.f;
        #pragma unroll
        for (int q = 0; q < 24; ++q) {
            const int a = t4*24 + q;
            z += b2f((unsigned short)xcb[i*104 + a]) * gw[a];
        }
        z += __shfl_xor(z, 1); z += __shfl_xor(z, 2);
        if (t4 == 0) red[i] = z + gb[0];
    }
    __syncthreads();
    if (wave == 0) {   // softmax over 128 nodes, one wave
        float v0 = red[lane], v1 = red[lane + 64];
        float m = fmaxf(v0, v1);
        #pragma unroll
        for (int off = 32; off > 0; off >>= 1) m = fmaxf(m, __shfl_xor(m, off));
        float e0 = expf(v0 - m), e1 = expf(v1 - m);
        float ssum = e0 + e1;
        #pragma unroll
        for (int off = 32; off > 0; off >>= 1) ssum += __shfl_xor(ssum, off);
        gate[lane] = e0 / ssum; gate[lane + 64] = e1 / ssum;
    }
    __syncthreads();

    // pooled GEMM: wave = i-tile, all 8 column tiles
    {
        f32x4 pacc[8];
        #pragma unroll
        for (int nt = 0; nt < 8; ++nt) pacc[nt] = (f32x4){0.f,0.f,0.f,0.f};
        #pragma unroll
        for (int ks = 0; ks < 3; ++ks) {
            const bf16x8 afp = *(const bf16x8*)&xcb[(wave*16+lm)*104 + ks*32 + kg*8];
            #pragma unroll
            for (int nt = 0; nt < 8; ++nt) {
                const bf16x8 bfp = *(const bf16x8*)&wp[40960 + (nt*16+lm)*96 + ks*32 + kg*8];
                pacc[nt] = MFMA16(afp, bfp, pacc[nt], 0,0,0);
            }
        }
        #pragma unroll
        for (int nt = 0; nt < 8; ++nt) {
            const float nbv = nb[nt*16+lm];
            float pv = 0.f;
            #pragma unroll
            for (int r = 0; r < 4; ++r)
                pv += gate[wave*16 + kg*4 + r] * tanhf(pacc[nt][r] + nbv);
            pv += __shfl_xor(pv, 16);
            pv += __shfl_xor(pv, 32);
            if (lane < 16) part[wave*128 + nt*16 + lm] = pv;
        }
    }
    __syncthreads();
    if (tid < H3) {
        float pooled = 0.f;
        #pragma unroll
        for (int w = 0; w < 8; ++w) pooled += part[w*128 + tid];
        tmpv[tid] = tanhf(pooled);                 // h3
    }
    __syncthreads();
    if (tid < H3) {
        float a4 = l3b[tid];
        for (int aa = 0; aa < H3; ++aa) a4 += tmpv[aa] * l3w[aa*H3 + tid];
        red[tid] = tanhf(a4);                      // h4
    }
    __syncthreads();
    if (tid < H4) {
        float a5 = l4b[tid];
        for (int aa = 0; aa < H3; ++aa) a5 += red[aa] * l4w[aa*H4 + tid];
        gate[tid] = tanhf(a5);                     // h5
    }
    __syncthreads();
    if (tid == 0) {
        float zo = l5b[0];
        for (int aa = 0; aa < H4; ++aa) zo += gate[aa] * l5w[aa];
        out[s] = 1.0f / (1.0f + expf(-zo));
    }
}

extern "C" void kernel_launch(void* const* d_in, const int* in_sizes, int n_in,
                              void* d_out, int out_size, void* d_ws, size_t ws_size,
                              hipStream_t stream)
{
    const float* A   = (const float*)d_in[0];
    const float* x   = (const float*)d_in[1];
    const float* w1  = (const float*)d_in[2];
    const float* lw1 = (const float*)d_in[3];
    const float* lb1 = (const float*)d_in[4];
    const float* w2  = (const float*)d_in[5];
    const float* lw2 = (const float*)d_in[6];
    const float* lb2 = (const float*)d_in[7];
    const float* gw  = (const float*)d_in[8];
    const float* gb  = (const float*)d_in[9];
    const float* nw  = (const float*)d_in[10];
    const float* nb  = (const float*)d_in[11];
    const float* l3w = (const float*)d_in[12];
    const float* l3b = (const float*)d_in[13];
    const float* l4w = (const float*)d_in[14];
    const float* l4b = (const float*)d_in[15];
    const float* l5w = (const float*)d_in[16];
    const float* l5b = (const float*)d_in[17];
    float* out = (float*)d_out;
    unsigned short* wp = (unsigned short*)d_ws;   // 106,496 B

    pack_weights<<<104, 512, 0, stream>>>(w1, lw1, w2, lw2, nw, wp);
    fused_kernel<<<SN, 512, 0, stream>>>(A, x, wp, lb1, lb2, gw, gb, nb,
                                         l3w, l3b, l4w, l4b, l5w, l5b, out);
}

// Round 12
// 105.085 us; speedup vs baseline: 1.3770x; 1.0175x over previous
//
#include <hip/hip_runtime.h>
#include <math.h>

#define SN  512
#define NN  128
#define CIN 32
#define CA  5
#define HH  64
#define YY  96
#define H3  128
#define H4  64
#define EPSF 1e-7f

typedef __attribute__((ext_vector_type(8))) short  bf16x8;
typedef __attribute__((ext_vector_type(4))) float  f32x4;
typedef __attribute__((ext_vector_type(4))) unsigned short us4;

#define MFMA16 __builtin_amdgcn_mfma_f32_16x16x32_bf16

__device__ inline unsigned short f2b(float f) {
    unsigned u = __builtin_bit_cast(unsigned, f);
    return (unsigned short)((u + 0x7FFFu + ((u >> 16) & 1u)) >> 16);
}
__device__ inline float b2f(unsigned short h) {
    unsigned u = ((unsigned)h) << 16;
    return __builtin_bit_cast(float, u);
}
__device__ inline bf16x8 pack8(float4 f0, float4 f1) {
    bf16x8 v;
    v[0]=(short)f2b(f0.x); v[1]=(short)f2b(f0.y); v[2]=(short)f2b(f0.z); v[3]=(short)f2b(f0.w);
    v[4]=(short)f2b(f1.x); v[5]=(short)f2b(f1.y); v[6]=(short)f2b(f1.z); v[7]=(short)f2b(f1.w);
    return v;
}
__device__ inline bf16x8 scale8(bf16x8 a, float s) {
    bf16x8 o;
    #pragma unroll
    for (int q = 0; q < 8; ++q)
        o[q] = (short)f2b(b2f((unsigned short)a[q]) * s);
    return o;
}

// PZ: 256 rows (c0..c3 x 64 b) x 128 shorts, XOR-swizzled 16B chunks. 64 KiB.
__device__ inline void pz_store4(short* PZ, int row, int colsh, const f32x4& pc) {
    int byo = (colsh*2) ^ ((row & 7) << 4);
    us4 w;
    w[0]=f2b(pc[0]); w[1]=f2b(pc[1]); w[2]=f2b(pc[2]); w[3]=f2b(pc[3]);
    *(us4*)&PZ[row*128 + (byo >> 1)] = w;
}
__device__ inline bf16x8 pz_load8(const short* PZ, int row, int colsh) {
    int byo = (colsh*2) ^ ((row & 7) << 4);
    return *(const bf16x8*)&PZ[row*128 + (byo >> 1)];
}

// ws pack (bf16): W1p [c5][b64][a32] @0 | W2p [c5][b64][a96] @10240 | nwp [b128][a96] @40960
__global__ __launch_bounds__(512) void pack_weights(
    const float* __restrict__ w1, const float* __restrict__ lw1,
    const float* __restrict__ w2, const float* __restrict__ lw2,
    const float* __restrict__ nw, unsigned short* __restrict__ wp)
{
    int t = blockIdx.x*512 + threadIdx.x;
    if (t < 10240) {
        int c = t >> 11, rem = t & 2047, b = rem >> 5, a = rem & 31;
        float v = (c < 4) ? w1[(a*64+b)*4 + c] : lw1[a*64+b];
        wp[t] = f2b(v);
    } else if (t < 40960) {
        int u = t - 10240;
        int c = u / 6144, rem = u % 6144, b = rem / 96, a = rem % 96;
        float v = (c < 4) ? w2[(a*64+b)*4 + c] : lw2[a*64+b];
        wp[t] = f2b(v);
    } else {
        int u = t - 40960;
        int b = u / 96, a = u % 96;
        wp[t] = f2b(nw[a*128 + b]);
    }
}

// One conv stage. Wave owns i/j-tile = wave*16 and ALL channels.
// P-phase: c=0..3 -> PZ swizzled; c=4 (linear/LW channel) stays in pc4 regs —
// its MFMA fragment (j=wave*16+kg*4+r, b=n*16+lm) is exactly the (i,b) element
// this thread adds in the epilogue (wave-local identity).
// Main: acc[n] accumulates over jt AND c (A-frags are prenormalized).
template<int CINY>
__device__ __forceinline__ void conv_core(
    const unsigned short* __restrict__ wp, const float* __restrict__ LB,
    short* PZ, const bf16x8 (&Af)[4][4], const bf16x8* yf,
    float (&v)[4][4], int wave, int lm, int kg)
{
    constexpr int K32  = CINY / 32;
    constexpr int WOFF = (CINY == 32) ? 0 : 10240;

    f32x4 pc4[4];
    #pragma unroll
    for (int c = 0; c < 5; ++c) {
        f32x4 pc[4];
        #pragma unroll
        for (int n = 0; n < 4; ++n) pc[n] = (f32x4){0.f,0.f,0.f,0.f};
        #pragma unroll
        for (int ks = 0; ks < K32; ++ks) {
            #pragma unroll
            for (int n = 0; n < 4; ++n) {
                const bf16x8 bw = *(const bf16x8*)&wp[WOFF + (c*64 + n*16+lm)*CINY + ks*32 + kg*8];
                pc[n] = MFMA16(yf[ks], bw, pc[n], 0,0,0);
            }
        }
        if (c < 4) {
            #pragma unroll
            for (int n = 0; n < 4; ++n)
                pz_store4(PZ, c*64 + n*16+lm, wave*16 + kg*4, pc[n]);
        } else {
            #pragma unroll
            for (int n = 0; n < 4; ++n) pc4[n] = pc[n];
        }
    }
    __syncthreads();

    f32x4 acc[4];
    #pragma unroll
    for (int n = 0; n < 4; ++n) acc[n] = (f32x4){0.f,0.f,0.f,0.f};
    #pragma unroll
    for (int jt = 0; jt < 4; ++jt) {
        #pragma unroll
        for (int c = 0; c < 4; ++c) {
            #pragma unroll
            for (int n = 0; n < 4; ++n) {
                const bf16x8 bp = pz_load8(PZ, c*64 + n*16+lm, jt*32 + kg*8);
                acc[n] = MFMA16(Af[jt][c], bp, acc[n], 0,0,0);
            }
        }
    }

    #pragma unroll
    for (int n = 0; n < 4; ++n) {
        const float lbv = LB[n*16 + lm];
        #pragma unroll
        for (int r = 0; r < 4; ++r)
            v[n][r] = tanhf(lbv + acc[n][r] + pc4[n][r]);
    }
    __syncthreads();   // all PZ reads done -> region reusable
}

__global__ __launch_bounds__(512, 2) void fused_kernel(
    const float* __restrict__ A, const float* __restrict__ x,
    const unsigned short* __restrict__ wp,
    const float* __restrict__ lb1, const float* __restrict__ lb2,
    const float* __restrict__ gw, const float* __restrict__ gb,
    const float* __restrict__ nb,
    const float* __restrict__ l3w, const float* __restrict__ l3b,
    const float* __restrict__ l4w, const float* __restrict__ l4b,
    const float* __restrict__ l5w, const float* __restrict__ l5b,
    float* __restrict__ out)
{
    __shared__ __align__(16) char smem[65536];
    short* PZ = (short*)smem;                 // 256 x 128 sh (full 64 KiB)
    // pool aliases (PZ dead by then)
    short* xcb  = (short*)smem;               // [128][104] bf16
    float* part = (float*)(smem + 26624);     // [8][128]
    float* gate = (float*)(smem + 30720);
    float* red  = (float*)(smem + 31232);
    float* tmpv = (float*)(smem + 31744);

    const int s = blockIdx.x, tid = threadIdx.x;
    const int wave = tid>>6, lane = tid&63, lm = lane&15, kg = lane>>4;
    const float* xg = x + (size_t)s*NN*CIN;

    const int jrow = wave*16 + lm;
    bf16x8 xfrag;
    {
        float4 f0 = *(const float4*)(xg + jrow*CIN + kg*8);
        float4 f1 = *(const float4*)(xg + jrow*CIN + kg*8 + 4);
        xfrag = pack8(f0, f1);
    }

    // ===== A prepass (wave-private, barrier-free): coalesced loads ->
    // de-interleave via scr -> raw Af; row-sums from the same loads + shuffles;
    // prenormalize Af by 1/(rowsum+eps). =====
    bf16x8 Af[4][4];
    {
        short* scr = PZ + wave*2688;          // wave-private [16][168]
        const float* Ab = A + ((size_t)(s*NN + wave*16))*NN*CA;
        const int r8 = lane>>3, l8 = lane&7;
        float sm[2][4];
        #pragma unroll
        for (int rh = 0; rh < 2; ++rh)
            #pragma unroll
            for (int c = 0; c < 4; ++c) sm[rh][c] = 0.f;

        #pragma unroll
        for (int jt = 0; jt < 4; ++jt) {
            #pragma unroll
            for (int rh = 0; rh < 2; ++rh) {
                const int r = r8 + rh*8;
                const float* rp = Ab + (size_t)r*(NN*CA) + jt*160 + l8*20;
                float4 q0 = *(const float4*)(rp);
                float4 q1 = *(const float4*)(rp+4);
                float4 q2 = *(const float4*)(rp+8);
                float4 q3 = *(const float4*)(rp+12);
                float4 q4 = *(const float4*)(rp+16);
                short* lr = scr + r*168;
                const int jb = 4*l8;
                lr[0*40 + jb+0] = (short)f2b(q0.x);
                lr[1*40 + jb+0] = (short)f2b(q0.y);
                lr[2*40 + jb+0] = (short)f2b(q0.z);
                lr[3*40 + jb+0] = (short)f2b(q0.w);
                lr[0*40 + jb+1] = (short)f2b(q1.y);
                lr[1*40 + jb+1] = (short)f2b(q1.z);
                lr[2*40 + jb+1] = (short)f2b(q1.w);
                lr[3*40 + jb+1] = (short)f2b(q2.x);
                lr[0*40 + jb+2] = (short)f2b(q2.z);
                lr[1*40 + jb+2] = (short)f2b(q2.w);
                lr[2*40 + jb+2] = (short)f2b(q3.x);
                lr[3*40 + jb+2] = (short)f2b(q3.y);
                lr[0*40 + jb+3] = (short)f2b(q3.w);
                lr[1*40 + jb+3] = (short)f2b(q4.x);
                lr[2*40 + jb+3] = (short)f2b(q4.y);
                lr[3*40 + jb+3] = (short)f2b(q4.z);
                sm[rh][0] += q0.x + q1.y + q2.z + q3.w;
                sm[rh][1] += q0.y + q1.z + q2.w + q4.x;
                sm[rh][2] += q0.z + q1.w + q3.x + q4.y;
                sm[rh][3] += q0.w + q2.x + q3.y + q4.z;
            }
            #pragma unroll
            for (int c = 0; c < 4; ++c)
                Af[jt][c] = *(const bf16x8*)&scr[lm*168 + c*40 + kg*8];
        }
        // reduce row-sums across the 8 lanes (l8) covering each row
        #pragma unroll
        for (int off = 1; off < 8; off <<= 1) {
            #pragma unroll
            for (int rh = 0; rh < 2; ++rh)
                #pragma unroll
                for (int c = 0; c < 4; ++c)
                    sm[rh][c] += __shfl_xor(sm[rh][c], off);
        }
        float* invL = (float*)scr;            // scr dead after Af extraction
        if (l8 == 0) {
            #pragma unroll
            for (int rh = 0; rh < 2; ++rh)
                #pragma unroll
                for (int c = 0; c < 4; ++c)
                    invL[(r8 + rh*8)*4 + c] = 1.0f/(sm[rh][c] + EPSF);
        }
        const f32x4 iv = *(const f32x4*)&invL[lm*4];
        #pragma unroll
        for (int jt = 0; jt < 4; ++jt)
            #pragma unroll
            for (int c = 0; c < 4; ++c)
                Af[jt][c] = scale8(Af[jt][c], iv[c]);
    }
    __syncthreads();   // scr region (PZ) fully consumed

    // ===== conv1 =====
    float v[4][4];
    {
        bf16x8 yf1[1] = {xfrag};
        conv_core<CIN>(wp, lb1, PZ, Af, yf1, v, wave, lm, kg);
    }

    // h1 bounce (wave-private): (i,b) regs -> (j,a) fragments
    bf16x8 yf2[3];
    {
        short* scr = PZ + wave*2688;
        #pragma unroll
        for (int n = 0; n < 4; ++n)
            #pragma unroll
            for (int r = 0; r < 4; ++r)
                scr[(kg*4+r)*72 + n*16 + lm] = (short)f2b(v[n][r]);
        yf2[0] = *(const bf16x8*)&scr[lm*72 + kg*8];
        yf2[1] = *(const bf16x8*)&scr[lm*72 + 32 + kg*8];
        yf2[2] = xfrag;
    }
    __syncthreads();   // scr reads done before conv2 P-writes to PZ

    // ===== conv2 =====
    conv_core<YY>(wp, lb2, PZ, Af, yf2, v, wave, lm, kg);

    // ===== pool + head =====
    #pragma unroll
    for (int n = 0; n < 4; ++n)
        #pragma unroll
        for (int r = 0; r < 4; ++r)
            xcb[(wave*16 + kg*4 + r)*104 + n*16 + lm] = (short)f2b(v[n][r]);
    for (int t = tid; t < NN*CIN; t += 512)
        xcb[(t>>5)*104 + 64 + (t&31)] = (short)f2b(xg[t]);
    __syncthreads();

    // gate logits: 4 threads per node
    {
        const int i = tid >> 2, t4 = tid & 3;
        float z = 0.f;
        #pragma unroll
        for (int q = 0; q < 24; ++q) {
            const int a = t4*24 + q;
            z += b2f((unsigned short)xcb[i*104 + a]) * gw[a];
        }
        z += __shfl_xor(z, 1); z += __shfl_xor(z, 2);
        if (t4 == 0) red[i] = z + gb[0];
    }
    __syncthreads();
    if (wave == 0) {   // softmax over 128 nodes, one wave
        float v0 = red[lane], v1 = red[lane + 64];
        float m = fmaxf(v0, v1);
        #pragma unroll
        for (int off = 32; off > 0; off >>= 1) m = fmaxf(m, __shfl_xor(m, off));
        float e0 = expf(v0 - m), e1 = expf(v1 - m);
        float ssum = e0 + e1;
        #pragma unroll
        for (int off = 32; off > 0; off >>= 1) ssum += __shfl_xor(ssum, off);
        gate[lane] = e0 / ssum; gate[lane + 64] = e1 / ssum;
    }
    __syncthreads();

    // pooled GEMM: wave = i-tile, all 8 column tiles
    {
        f32x4 pacc[8];
        #pragma unroll
        for (int nt = 0; nt < 8; ++nt) pacc[nt] = (f32x4){0.f,0.f,0.f,0.f};
        #pragma unroll
        for (int ks = 0; ks < 3; ++ks) {
            const bf16x8 afp = *(const bf16x8*)&xcb[(wave*16+lm)*104 + ks*32 + kg*8];
            #pragma unroll
            for (int nt = 0; nt < 8; ++nt) {
                const bf16x8 bfp = *(const bf16x8*)&wp[40960 + (nt*16+lm)*96 + ks*32 + kg*8];
                pacc[nt] = MFMA16(afp, bfp, pacc[nt], 0,0,0);
            }
        }
        #pragma unroll
        for (int nt = 0; nt < 8; ++nt) {
            const float nbv = nb[nt*16+lm];
            float pv = 0.f;
            #pragma unroll
            for (int r = 0; r < 4; ++r)
                pv += gate[wave*16 + kg*4 + r] * tanhf(pacc[nt][r] + nbv);
            pv += __shfl_xor(pv, 16);
            pv += __shfl_xor(pv, 32);
            if (lane < 16) part[wave*128 + nt*16 + lm] = pv;
        }
    }
    __syncthreads();
    if (tid < H3) {
        float pooled = 0.f;
        #pragma unroll
        for (int w = 0; w < 8; ++w) pooled += part[w*128 + tid];
        tmpv[tid] = tanhf(pooled);                 // h3
    }
    __syncthreads();
    if (tid < H3) {
        float a4 = l3b[tid];
        for (int aa = 0; aa < H3; ++aa) a4 += tmpv[aa] * l3w[aa*H3 + tid];
        red[tid] = tanhf(a4);                      // h4
    }
    __syncthreads();
    if (tid < H4) {
        float a5 = l4b[tid];
        for (int aa = 0; aa < H3; ++aa) a5 += red[aa] * l4w[aa*H4 + tid];
        gate[tid] = tanhf(a5);                     // h5
    }
    __syncthreads();
    if (tid == 0) {
        float zo = l5b[0];
        for (int aa = 0; aa < H4; ++aa) zo += gate[aa] * l5w[aa];
        out[s] = 1.0f / (1.0f + expf(-zo));
    }
}

extern "C" void kernel_launch(void* const* d_in, const int* in_sizes, int n_in,
                              void* d_out, int out_size, void* d_ws, size_t ws_size,
                              hipStream_t stream)
{
    const float* A   = (const float*)d_in[0];
    const float* x   = (const float*)d_in[1];
    const float* w1  = (const float*)d_in[2];
    const float* lw1 = (const float*)d_in[3];
    const float* lb1 = (const float*)d_in[4];
    const float* w2  = (const float*)d_in[5];
    const float* lw2 = (const float*)d_in[6];
    const float* lb2 = (const float*)d_in[7];
    const float* gw  = (const float*)d_in[8];
    const float* gb  = (const float*)d_in[9];
    const float* nw  = (const float*)d_in[10];
    const float* nb  = (const float*)d_in[11];
    const float* l3w = (const float*)d_in[12];
    const float* l3b = (const float*)d_in[13];
    const float* l4w = (const float*)d_in[14];
    const float* l4b = (const float*)d_in[15];
    const float* l5w = (const float*)d_in[16];
    const float* l5b = (const float*)d_in[17];
    float* out = (float*)d_out;
    unsigned short* wp = (unsigned short*)d_ws;   // 106,496 B

    pack_weights<<<104, 512, 0, stream>>>(w1, lw1, w2, lw2, nw, wp);
    fused_kernel<<<SN, 512, 0, stream>>>(A, x, wp, lb1, lb2, gw, gb, nb,
                                         l3w, l3b, l4w, l4b, l5w, l5b, out);
}

// Round 13
// 83.803 us; speedup vs baseline: 1.7267x; 1.2540x over previous
//
#include <hip/hip_runtime.h>
#include <math.h>

#define SN  512
#define NN  128
#define CIN 32
#define CA  5
#define HH  64
#define YY  96
#define H3  128
#define H4  64
#define EPSF 1e-7f

typedef __attribute__((ext_vector_type(8))) short  bf16x8;
typedef __attribute__((ext_vector_type(4))) float  f32x4;
typedef __attribute__((ext_vector_type(4))) unsigned short us4;

#define MFMA16 __builtin_amdgcn_mfma_f32_16x16x32_bf16

__device__ inline unsigned short f2b(float f) {
    unsigned u = __builtin_bit_cast(unsigned, f);
    return (unsigned short)((u + 0x7FFFu + ((u >> 16) & 1u)) >> 16);
}
__device__ inline float b2f(unsigned short h) {
    unsigned u = ((unsigned)h) << 16;
    return __builtin_bit_cast(float, u);
}
__device__ inline bf16x8 pack8(float4 f0, float4 f1) {
    bf16x8 v;
    v[0]=(short)f2b(f0.x); v[1]=(short)f2b(f0.y); v[2]=(short)f2b(f0.z); v[3]=(short)f2b(f0.w);
    v[4]=(short)f2b(f1.x); v[5]=(short)f2b(f1.y); v[6]=(short)f2b(f1.z); v[7]=(short)f2b(f1.w);
    return v;
}
__device__ inline bf16x8 scale8(bf16x8 a, float s) {
    bf16x8 o;
    #pragma unroll
    for (int q = 0; q < 8; ++q)
        o[q] = (short)f2b(b2f((unsigned short)a[q]) * s);
    return o;
}
__device__ inline bf16x8 load_xfrag(const float* xg, int row, int kg) {
    float4 f0 = *(const float4*)(xg + row*CIN + kg*8);
    float4 f1 = *(const float4*)(xg + row*CIN + kg*8 + 4);
    return pack8(f0, f1);
}

// PZ: 256 rows (c0..c3 x 64 b) x 128 shorts, XOR-swizzled 16B chunks. 64 KiB.
__device__ inline void pz_store4(short* PZ, int row, int colsh, const f32x4& pc) {
    int byo = (colsh*2) ^ ((row & 7) << 4);
    us4 w;
    w[0]=f2b(pc[0]); w[1]=f2b(pc[1]); w[2]=f2b(pc[2]); w[3]=f2b(pc[3]);
    *(us4*)&PZ[row*128 + (byo >> 1)] = w;
}
__device__ inline bf16x8 pz_load8(const short* PZ, int row, int colsh) {
    int byo = (colsh*2) ^ ((row & 7) << 4);
    return *(const bf16x8*)&PZ[row*128 + (byo >> 1)];
}

// ws pack (bf16): W1p [c5][b64][a32] @0 | W2p [c5][b64][a96] @10240 | nwp [b128][a96] @40960
__global__ __launch_bounds__(512) void pack_weights(
    const float* __restrict__ w1, const float* __restrict__ lw1,
    const float* __restrict__ w2, const float* __restrict__ lw2,
    const float* __restrict__ nw, unsigned short* __restrict__ wp)
{
    int t = blockIdx.x*512 + threadIdx.x;
    if (t < 10240) {
        int c = t >> 11, rem = t & 2047, b = rem >> 5, a = rem & 31;
        float v = (c < 4) ? w1[(a*64+b)*4 + c] : lw1[a*64+b];
        wp[t] = f2b(v);
    } else if (t < 40960) {
        int u = t - 10240;
        int c = u / 6144, rem = u % 6144, b = rem / 96, a = rem % 96;
        float v = (c < 4) ? w2[(a*64+b)*4 + c] : lw2[a*64+b];
        wp[t] = f2b(v);
    } else {
        int u = t - 40960;
        int b = u / 96, a = u % 96;
        wp[t] = f2b(nw[a*128 + b]);
    }
}

// One conv stage. Wave owns i/j-tile = wave*16 and ALL channels.
// P-phase: c=4 (linear/LW) computed FIRST directly into acc (its MFMA fragment
// (j=wave*16+kg*4+r, b=n*16+lm) is exactly the (i,b) element this thread needs
// in the epilogue — wave-local identity); c=0..3 -> PZ swizzled.
// Main: acc[n] accumulates over jt AND c (A-frags are prenormalized).
template<int CINY>
__device__ __forceinline__ void conv_core(
    const unsigned short* __restrict__ wp, const float* __restrict__ LB,
    short* PZ, const bf16x8 (&Af)[4][4], const bf16x8* yf,
    float (&v)[4][4], int wave, int lm, int kg)
{
    constexpr int K32  = CINY / 32;
    constexpr int WOFF = (CINY == 32) ? 0 : 10240;

    f32x4 acc[4];
    #pragma unroll
    for (int n = 0; n < 4; ++n) acc[n] = (f32x4){0.f,0.f,0.f,0.f};

    // c = 4 (linear channel) -> acc init
    #pragma unroll
    for (int ks = 0; ks < K32; ++ks) {
        #pragma unroll
        for (int n = 0; n < 4; ++n) {
            const bf16x8 bw = *(const bf16x8*)&wp[WOFF + (4*64 + n*16+lm)*CINY + ks*32 + kg*8];
            acc[n] = MFMA16(yf[ks], bw, acc[n], 0,0,0);
        }
    }
    // c = 0..3 -> PZ
    #pragma unroll
    for (int c = 0; c < 4; ++c) {
        f32x4 pc[4];
        #pragma unroll
        for (int n = 0; n < 4; ++n) pc[n] = (f32x4){0.f,0.f,0.f,0.f};
        #pragma unroll
        for (int ks = 0; ks < K32; ++ks) {
            #pragma unroll
            for (int n = 0; n < 4; ++n) {
                const bf16x8 bw = *(const bf16x8*)&wp[WOFF + (c*64 + n*16+lm)*CINY + ks*32 + kg*8];
                pc[n] = MFMA16(yf[ks], bw, pc[n], 0,0,0);
            }
        }
        #pragma unroll
        for (int n = 0; n < 4; ++n)
            pz_store4(PZ, c*64 + n*16+lm, wave*16 + kg*4, pc[n]);
    }
    __syncthreads();

    #pragma unroll
    for (int jt = 0; jt < 4; ++jt) {
        #pragma unroll
        for (int c = 0; c < 4; ++c) {
            #pragma unroll
            for (int n = 0; n < 4; ++n) {
                const bf16x8 bp = pz_load8(PZ, c*64 + n*16+lm, jt*32 + kg*8);
                acc[n] = MFMA16(Af[jt][c], bp, acc[n], 0,0,0);
            }
        }
    }

    #pragma unroll
    for (int n = 0; n < 4; ++n) {
        const float lbv = LB[n*16 + lm];
        #pragma unroll
        for (int r = 0; r < 4; ++r)
            v[n][r] = tanhf(lbv + acc[n][r]);
    }
    __syncthreads();   // all PZ reads done -> region reusable
}

__global__ __launch_bounds__(512, 4) void fused_kernel(
    const float* __restrict__ A, const float* __restrict__ x,
    const unsigned short* __restrict__ wp,
    const float* __restrict__ lb1, const float* __restrict__ lb2,
    const float* __restrict__ gw, const float* __restrict__ gb,
    const float* __restrict__ nb,
    const float* __restrict__ l3w, const float* __restrict__ l3b,
    const float* __restrict__ l4w, const float* __restrict__ l4b,
    const float* __restrict__ l5w, const float* __restrict__ l5b,
    float* __restrict__ out)
{
    __shared__ __align__(16) char smem[65536];
    short* PZ = (short*)smem;                 // 256 x 128 sh (full 64 KiB)
    // pool aliases (PZ dead by then)
    short* xcb  = (short*)smem;               // [128][104] bf16
    float* part = (float*)(smem + 26624);     // [8][128]
    float* gate = (float*)(smem + 30720);
    float* red  = (float*)(smem + 31232);
    float* tmpv = (float*)(smem + 31744);

    const int s = blockIdx.x, tid = threadIdx.x;
    const int wave = tid>>6, lane = tid&63, lm = lane&15, kg = lane>>4;
    const float* xg = x + (size_t)s*NN*CIN;
    const int jrow = wave*16 + lm;

    // ===== A prepass (wave-private, barrier-free): coalesced loads ->
    // de-interleave via scr -> raw Af; row-sums from the same loads + shuffles;
    // prenormalize Af by 1/(rowsum+eps). =====
    bf16x8 Af[4][4];
    {
        short* scr = PZ + wave*2688;          // wave-private [16][168]
        const float* Ab = A + ((size_t)(s*NN + wave*16))*NN*CA;
        const int r8 = lane>>3, l8 = lane&7;
        float sm[2][4];
        #pragma unroll
        for (int rh = 0; rh < 2; ++rh)
            #pragma unroll
            for (int c = 0; c < 4; ++c) sm[rh][c] = 0.f;

        #pragma unroll
        for (int jt = 0; jt < 4; ++jt) {
            #pragma unroll
            for (int rh = 0; rh < 2; ++rh) {
                const int r = r8 + rh*8;
                const float* rp = Ab + (size_t)r*(NN*CA) + jt*160 + l8*20;
                float4 q0 = *(const float4*)(rp);
                float4 q1 = *(const float4*)(rp+4);
                float4 q2 = *(const float4*)(rp+8);
                float4 q3 = *(const float4*)(rp+12);
                float4 q4 = *(const float4*)(rp+16);
                short* lr = scr + r*168;
                const int jb = 4*l8;
                lr[0*40 + jb+0] = (short)f2b(q0.x);
                lr[1*40 + jb+0] = (short)f2b(q0.y);
                lr[2*40 + jb+0] = (short)f2b(q0.z);
                lr[3*40 + jb+0] = (short)f2b(q0.w);
                lr[0*40 + jb+1] = (short)f2b(q1.y);
                lr[1*40 + jb+1] = (short)f2b(q1.z);
                lr[2*40 + jb+1] = (short)f2b(q1.w);
                lr[3*40 + jb+1] = (short)f2b(q2.x);
                lr[0*40 + jb+2] = (short)f2b(q2.z);
                lr[1*40 + jb+2] = (short)f2b(q2.w);
                lr[2*40 + jb+2] = (short)f2b(q3.x);
                lr[3*40 + jb+2] = (short)f2b(q3.y);
                lr[0*40 + jb+3] = (short)f2b(q3.w);
                lr[1*40 + jb+3] = (short)f2b(q4.x);
                lr[2*40 + jb+3] = (short)f2b(q4.y);
                lr[3*40 + jb+3] = (short)f2b(q4.z);
                sm[rh][0] += q0.x + q1.y + q2.z + q3.w;
                sm[rh][1] += q0.y + q1.z + q2.w + q4.x;
                sm[rh][2] += q0.z + q1.w + q3.x + q4.y;
                sm[rh][3] += q0.w + q2.x + q3.y + q4.z;
            }
            #pragma unroll
            for (int c = 0; c < 4; ++c)
                Af[jt][c] = *(const bf16x8*)&scr[lm*168 + c*40 + kg*8];
        }
        // reduce row-sums across the 8 lanes (l8) covering each row
        #pragma unroll
        for (int off = 1; off < 8; off <<= 1) {
            #pragma unroll
            for (int rh = 0; rh < 2; ++rh)
                #pragma unroll
                for (int c = 0; c < 4; ++c)
                    sm[rh][c] += __shfl_xor(sm[rh][c], off);
        }
        float* invL = (float*)scr;            // scr dead after Af extraction
        if (l8 == 0) {
            #pragma unroll
            for (int rh = 0; rh < 2; ++rh)
                #pragma unroll
                for (int c = 0; c < 4; ++c)
                    invL[(r8 + rh*8)*4 + c] = 1.0f/(sm[rh][c] + EPSF);
        }
        const f32x4 iv = *(const f32x4*)&invL[lm*4];
        #pragma unroll
        for (int jt = 0; jt < 4; ++jt)
            #pragma unroll
            for (int c = 0; c < 4; ++c)
                Af[jt][c] = scale8(Af[jt][c], iv[c]);
    }
    __syncthreads();   // scr region (PZ) fully consumed

    // ===== conv1 =====
    float v[4][4];
    {
        bf16x8 yf1[1] = { load_xfrag(xg, jrow, kg) };
        conv_core<CIN>(wp, lb1, PZ, Af, yf1, v, wave, lm, kg);
    }

    // h1 bounce (wave-private): (i,b) regs -> (j,a) fragments
    bf16x8 yf2[3];
    {
        short* scr = PZ + wave*2688;
        #pragma unroll
        for (int n = 0; n < 4; ++n)
            #pragma unroll
            for (int r = 0; r < 4; ++r)
                scr[(kg*4+r)*72 + n*16 + lm] = (short)f2b(v[n][r]);
        yf2[0] = *(const bf16x8*)&scr[lm*72 + kg*8];
        yf2[1] = *(const bf16x8*)&scr[lm*72 + 32 + kg*8];
        yf2[2] = load_xfrag(xg, jrow, kg);
    }
    __syncthreads();   // scr reads done before conv2 P-writes to PZ

    // ===== conv2 =====
    conv_core<YY>(wp, lb2, PZ, Af, yf2, v, wave, lm, kg);

    // ===== pool + head =====
    #pragma unroll
    for (int n = 0; n < 4; ++n)
        #pragma unroll
        for (int r = 0; r < 4; ++r)
            xcb[(wave*16 + kg*4 + r)*104 + n*16 + lm] = (short)f2b(v[n][r]);
    for (int t = tid; t < NN*CIN; t += 512)
        xcb[(t>>5)*104 + 64 + (t&31)] = (short)f2b(xg[t]);
    __syncthreads();

    // gate logits: 4 threads per node
    {
        const int i = tid >> 2, t4 = tid & 3;
        float z = 0.f;
        #pragma unroll
        for (int q = 0; q < 24; ++q) {
            const int a = t4*24 + q;
            z += b2f((unsigned short)xcb[i*104 + a]) * gw[a];
        }
        z += __shfl_xor(z, 1); z += __shfl_xor(z, 2);
        if (t4 == 0) red[i] = z + gb[0];
    }
    __syncthreads();
    if (wave == 0) {   // softmax over 128 nodes, one wave
        float v0 = red[lane], v1 = red[lane + 64];
        float m = fmaxf(v0, v1);
        #pragma unroll
        for (int off = 32; off > 0; off >>= 1) m = fmaxf(m, __shfl_xor(m, off));
        float e0 = expf(v0 - m), e1 = expf(v1 - m);
        float ssum = e0 + e1;
        #pragma unroll
        for (int off = 32; off > 0; off >>= 1) ssum += __shfl_xor(ssum, off);
        gate[lane] = e0 / ssum; gate[lane + 64] = e1 / ssum;
    }
    __syncthreads();

    // pooled GEMM: wave = i-tile, all 8 column tiles
    {
        f32x4 pacc[8];
        #pragma unroll
        for (int nt = 0; nt < 8; ++nt) pacc[nt] = (f32x4){0.f,0.f,0.f,0.f};
        #pragma unroll
        for (int ks = 0; ks < 3; ++ks) {
            const bf16x8 afp = *(const bf16x8*)&xcb[(wave*16+lm)*104 + ks*32 + kg*8];
            #pragma unroll
            for (int nt = 0; nt < 8; ++nt) {
                const bf16x8 bfp = *(const bf16x8*)&wp[40960 + (nt*16+lm)*96 + ks*32 + kg*8];
                pacc[nt] = MFMA16(afp, bfp, pacc[nt], 0,0,0);
            }
        }
        #pragma unroll
        for (int nt = 0; nt < 8; ++nt) {
            const float nbv = nb[nt*16+lm];
            float pv = 0.f;
            #pragma unroll
            for (int r = 0; r < 4; ++r)
                pv += gate[wave*16 + kg*4 + r] * tanhf(pacc[nt][r] + nbv);
            pv += __shfl_xor(pv, 16);
            pv += __shfl_xor(pv, 32);
            if (lane < 16) part[wave*128 + nt*16 + lm] = pv;
        }
    }
    __syncthreads();
    if (tid < H3) {
        float pooled = 0.f;
        #pragma unroll
        for (int w = 0; w < 8; ++w) pooled += part[w*128 + tid];
        tmpv[tid] = tanhf(pooled);                 // h3
    }
    __syncthreads();
    if (tid < H3) {
        float a4 = l3b[tid];
        for (int aa = 0; aa < H3; ++aa) a4 += tmpv[aa] * l3w[aa*H3 + tid];
        red[tid] = tanhf(a4);                      // h4
    }
    __syncthreads();
    if (tid < H4) {
        float a5 = l4b[tid];
        for (int aa = 0; aa < H3; ++aa) a5 += red[aa] * l4w[aa*H4 + tid];
        gate[tid] = tanhf(a5);                     // h5
    }
    __syncthreads();
    if (tid == 0) {
        float zo = l5b[0];
        for (int aa = 0; aa < H4; ++aa) zo += gate[aa] * l5w[aa];
        out[s] = 1.0f / (1.0f + expf(-zo));
    }
}

extern "C" void kernel_launch(void* const* d_in, const int* in_sizes, int n_in,
                              void* d_out, int out_size, void* d_ws, size_t ws_size,
                              hipStream_t stream)
{
    const float* A   = (const float*)d_in[0];
    const float* x   = (const float*)d_in[1];
    const float* w1  = (const float*)d_in[2];
    const float* lw1 = (const float*)d_in[3];
    const float* lb1 = (const float*)d_in[4];
    const float* w2  = (const float*)d_in[5];
    const float* lw2 = (const float*)d_in[6];
    const float* lb2 = (const float*)d_in[7];
    const float* gw  = (const float*)d_in[8];
    const float* gb  = (const float*)d_in[9];
    const float* nw  = (const float*)d_in[10];
    const float* nb  = (const float*)d_in[11];
    const float* l3w = (const float*)d_in[12];
    const float* l3b = (const float*)d_in[13];
    const float* l4w = (const float*)d_in[14];
    const float* l4b = (const float*)d_in[15];
    const float* l5w = (const float*)d_in[16];
    const float* l5b = (const float*)d_in[17];
    float* out = (float*)d_out;
    unsigned short* wp = (unsigned short*)d_ws;   // 106,496 B

    pack_weights<<<104, 512, 0, stream>>>(w1, lw1, w2, lw2, nw, wp);
    fused_kernel<<<SN, 512, 0, stream>>>(A, x, wp, lb1, lb2, gw, gb, nb,
                                         l3w, l3b, l4w, l4b, l5w, l5b, out);
}